// Round 2
// baseline (1553.240 us; speedup 1.0000x reference)
//
#include <hip/hip_runtime.h>
#include <hip/hip_bf16.h>

// Performer (ORF linear attention) + out-proj + residual + LayerNorm.
// Round 2: compact workspace (226 MB), ws_size guard. fp32 vector GEMMs still.

typedef float f4 __attribute__((ext_vector_type(4)));

#define B_  4
#define L_  2048
#define H_  16
#define D_  64
#define DM_ 1024
#define R_  256
#define C_  64           // scan chunk size
#define NC_ (L_ / C_)    // 32 chunks
#define M_  (B_ * L_)    // 8192 rows
#define M2_ (M_ * H_)    // 131072 head-rows

static __device__ __forceinline__ unsigned short f2bu(float x) {
    __hip_bfloat16 h = __float2bfloat16(x);
    return *(unsigned short*)&h;
}

// ---------------------------------------------------------------------------
// C[M,N] = A[M,K] @ B[N,K]^T  (+ optional residual add)
// ---------------------------------------------------------------------------
__launch_bounds__(256)
__global__ void gemm_bt(const float* __restrict__ A, const float* __restrict__ Bm,
                        const float* __restrict__ resid, float* __restrict__ C,
                        int M, int N, int K, int do_resid) {
    __shared__ __align__(16) float As[16][68];
    __shared__ __align__(16) float Bs[16][68];
    const int t  = threadIdx.x;
    const int tx = t & 15, ty = t >> 4;
    const int row0 = blockIdx.y * 64, col0 = blockIdx.x * 64;
    const int lr = t >> 2, lc = (t & 3) * 4;

    f4 acc[4] = {};
    for (int kk = 0; kk < K; kk += 16) {
        f4 av = *(const f4*)&A [(size_t)(row0 + lr) * K + kk + lc];
        f4 bv = *(const f4*)&Bm[(size_t)(col0 + lr) * K + kk + lc];
#pragma unroll
        for (int q = 0; q < 4; ++q) { As[lc + q][lr] = av[q]; Bs[lc + q][lr] = bv[q]; }
        __syncthreads();
#pragma unroll
        for (int k2 = 0; k2 < 16; ++k2) {
            f4 a = *(const f4*)&As[k2][ty * 4];
            f4 b = *(const f4*)&Bs[k2][tx * 4];
            acc[0] += b * a[0];
            acc[1] += b * a[1];
            acc[2] += b * a[2];
            acc[3] += b * a[3];
        }
        __syncthreads();
    }
#pragma unroll
    for (int i = 0; i < 4; ++i) {
        size_t off = (size_t)(row0 + ty * 4 + i) * N + col0 + tx * 4;
        f4 v = acc[i];
        if (do_resid) v += *(const f4*)&resid[off];
        *(f4*)&C[off] = v;
    }
}

// ---------------------------------------------------------------------------
// ORF features: out[m,r] = sqrt(2/R) * cos( dot(X[m,0:64], omega[r,0:64]) + b[r] )
// ---------------------------------------------------------------------------
__launch_bounds__(256)
__global__ void feat_kernel(const float* __restrict__ X, const float* __restrict__ omega,
                            const float* __restrict__ bvec, __hip_bfloat16* __restrict__ out) {
    __shared__ __align__(16) float Xs[32][64];
    const int t  = threadIdx.x;
    const int m0 = blockIdx.x * 32;
#pragma unroll
    for (int m = 0; m < 8; ++m) {
        int flat = m * 256 + t;
        int r = flat >> 6, c = flat & 63;
        Xs[r][c] = X[(size_t)(m0 + r) * 64 + c];
    }
    f4 om[16];
#pragma unroll
    for (int j = 0; j < 16; ++j) om[j] = *(const f4*)&omega[(size_t)t * 64 + j * 4];
    const float bb = bvec[t];
    __syncthreads();

    const float scale = 0.08838834764831845f;  // sqrt(2/256)
    for (int m = 0; m < 32; ++m) {
        float s = bb;
#pragma unroll
        for (int j = 0; j < 16; ++j) {
            f4 xv = *(const f4*)&Xs[m][j * 4];
            s += om[j][0] * xv[0] + om[j][1] * xv[1] + om[j][2] * xv[2] + om[j][3] * xv[3];
        }
        out[(size_t)(m0 + m) * R_ + t] = __float2bfloat16(scale * __cosf(s));
    }
}

// ---------------------------------------------------------------------------
// passA: per (b,h,chunk): KV[r][d] = sum_l kp[l][r]*v[l][d]; ksum[r]. KV in bf16.
// ---------------------------------------------------------------------------
__launch_bounds__(256)
__global__ void passA(const __hip_bfloat16* __restrict__ kp, const float* __restrict__ v,
                      __hip_bfloat16* __restrict__ kv, float* __restrict__ ksum) {
    __shared__ __align__(16) float Vs[C_][64];
    const int c = blockIdx.x, h = blockIdx.y, bz = blockIdx.z;
    const int t = threadIdx.x;  // r
    const int l0 = c * C_;
#pragma unroll
    for (int m = 0; m < (C_ * 64) / 256; ++m) {
        int flat = m * 256 + t;
        int r = flat >> 6, cc = flat & 63;
        Vs[r][cc] = v[(size_t)(bz * L_ + l0 + r) * DM_ + h * 64 + cc];
    }
    __syncthreads();

    f4 acc[16] = {};
    float ks = 0.f;
    for (int l = 0; l < C_; ++l) {
        float kpv = __bfloat162float(kp[((size_t)(bz * L_ + l0 + l) * H_ + h) * R_ + t]);
        ks += kpv;
#pragma unroll
        for (int d4 = 0; d4 < 16; ++d4) {
            f4 vv = *(const f4*)&Vs[l][d4 * 4];
            acc[d4] += vv * kpv;
        }
    }
    const int bh = bz * H_ + h;
    size_t base = ((size_t)(bh * NC_ + c) * R_ + t) * 64;
#pragma unroll
    for (int d4 = 0; d4 < 16; ++d4) {
        ushort4 pk;
        pk.x = f2bu(acc[d4][0]); pk.y = f2bu(acc[d4][1]);
        pk.z = f2bu(acc[d4][2]); pk.w = f2bu(acc[d4][3]);
        *(ushort4*)&kv[base + d4 * 4] = pk;
    }
    ksum[(size_t)(bh * NC_ + c) * R_ + t] = ks;
}

// ---------------------------------------------------------------------------
// passB: in-place exclusive prefix over chunks (kv bf16, running sum fp32).
// ---------------------------------------------------------------------------
__launch_bounds__(256)
__global__ void passB(__hip_bfloat16* __restrict__ kv, float* __restrict__ ksum) {
    const int dg = blockIdx.x, h = blockIdx.y, bz = blockIdx.z;
    const int r = threadIdx.x;
    const int bh = bz * H_ + h;
    float run[16] = {};
    for (int c = 0; c < NC_; ++c) {
        size_t base = ((size_t)(bh * NC_ + c) * R_ + r) * 64 + dg * 16;
#pragma unroll
        for (int d = 0; d < 16; ++d) {
            float tmp = __bfloat162float(kv[base + d]);
            unsigned short u = f2bu(run[d]);
            kv[base + d] = *(__hip_bfloat16*)&u;
            run[d] += tmp;
        }
    }
    if (dg == 0) {
        float rz = 0.f;
        for (int c = 0; c < NC_; ++c) {
            size_t idx = (size_t)(bh * NC_ + c) * R_ + r;
            float tmp = ksum[idx];
            ksum[idx] = rz;
            rz += tmp;
        }
    }
}

// ---------------------------------------------------------------------------
// passC: per (b,h,chunk):
//   A = mask(QP @ KP^T); den = rowsum(A) + QP.zpref
//   out = (A @ V + QP @ Spref) / (max(den,1e-6)+1e-6)   [writes attn over v]
// ---------------------------------------------------------------------------
__launch_bounds__(256)
__global__ void passC(const __hip_bfloat16* __restrict__ qp, const __hip_bfloat16* __restrict__ kp,
                      const float* __restrict__ v, const __hip_bfloat16* __restrict__ kvpref,
                      const float* __restrict__ zpref, float* __restrict__ attn) {
    __shared__ __align__(16) float As[64][65];
    __shared__ __align__(16) float st1[32][68];
    __shared__ __align__(16) float st2[32][68];
    __shared__ __align__(16) float Vs[64][64];
    __shared__ float zs[R_];
    __shared__ float den[64];

    const int c = blockIdx.x, h = blockIdx.y, bz = blockIdx.z;
    const int t = threadIdx.x;
    const int tx = t & 15, ty = t >> 4;
    const int l0 = c * C_;
    const int bh = bz * H_ + h;

    zs[t] = zpref[(size_t)(bh * NC_ + c) * R_ + t];

    // ---- phase A: scores --------------------------------------------------
    f4 accA[4] = {};
    float denz = 0.f;
    for (int s = 0; s < 8; ++s) {
#pragma unroll
        for (int m = 0; m < 8; ++m) {
            int flat = m * 256 + t;
            int i = flat >> 5, k = flat & 31;
            size_t rowb = ((size_t)(bz * L_ + l0 + i) * H_ + h) * R_ + s * 32 + k;
            st1[k][i] = __bfloat162float(qp[rowb]);
            st2[k][i] = __bfloat162float(kp[rowb]);
        }
        __syncthreads();
#pragma unroll
        for (int k2 = 0; k2 < 32; ++k2) {
            f4 a = *(const f4*)&st1[k2][ty * 4];
            f4 b = *(const f4*)&st2[k2][tx * 4];
            accA[0] += b * a[0];
            accA[1] += b * a[1];
            accA[2] += b * a[2];
            accA[3] += b * a[3];
        }
        if (t < 64) {
#pragma unroll
            for (int k2 = 0; k2 < 32; ++k2) denz += st1[k2][t] * zs[s * 32 + k2];
        }
        __syncthreads();
    }
    // masked scores -> LDS
#pragma unroll
    for (int ii = 0; ii < 4; ++ii)
#pragma unroll
        for (int jj = 0; jj < 4; ++jj) {
            int i = ty * 4 + ii, j = tx * 4 + jj;
            As[i][j] = (j <= i) ? accA[ii][jj] : 0.f;
        }
    // stage V chunk
#pragma unroll
    for (int m = 0; m < 16; ++m) {
        int flat = m * 256 + t;
        int j = flat >> 6, d = flat & 63;
        Vs[j][d] = v[(size_t)(bz * L_ + l0 + j) * DM_ + h * 64 + d];
    }
    __syncthreads();

    if (t < 64) {
        float di = 0.f;
        for (int j = 0; j <= t; ++j) di += As[t][j];
        den[t] = fmaxf(denz + di, 1e-6f) + 1e-6f;
    }

    // ---- phase B: outputs. thread (tx,ty): i = ty*4+ii, d = tx*4 ----------
    f4 accO[4] = {};
#pragma unroll
    for (int j = 0; j < 64; ++j) {
        f4 vv = *(const f4*)&Vs[j][tx * 4];
        accO[0] += vv * As[ty * 4 + 0][j];
        accO[1] += vv * As[ty * 4 + 1][j];
        accO[2] += vv * As[ty * 4 + 2][j];
        accO[3] += vv * As[ty * 4 + 3][j];
    }
    for (int s = 0; s < 8; ++s) {
#pragma unroll
        for (int m = 0; m < 8; ++m) {
            int flat = m * 256 + t;
            int i = flat >> 5, k = flat & 31;
            st1[k][i] = __bfloat162float(qp[((size_t)(bz * L_ + l0 + i) * H_ + h) * R_ + s * 32 + k]);
        }
#pragma unroll
        for (int m = 0; m < 8; ++m) {
            int flat = m * 256 + t;
            int k = flat >> 6, d = flat & 63;
            st2[k][d] = __bfloat162float(kvpref[((size_t)(bh * NC_ + c) * R_ + s * 32 + k) * 64 + d]);
        }
        __syncthreads();
#pragma unroll
        for (int k2 = 0; k2 < 32; ++k2) {
            f4 qv = *(const f4*)&st1[k2][ty * 4];
            f4 sv = *(const f4*)&st2[k2][tx * 4];
            accO[0] += sv * qv[0];
            accO[1] += sv * qv[1];
            accO[2] += sv * qv[2];
            accO[3] += sv * qv[3];
        }
        __syncthreads();
    }
#pragma unroll
    for (int ii = 0; ii < 4; ++ii) {
        float inv = 1.f / den[ty * 4 + ii];
        f4 o = accO[ii] * inv;
        *(f4*)&attn[(size_t)(bz * L_ + l0 + ty * 4 + ii) * DM_ + h * 64 + tx * 4] = o;
    }
}

// ---------------------------------------------------------------------------
// In-place row LayerNorm over last dim (1024), eps=1e-5 (population variance).
// ---------------------------------------------------------------------------
__launch_bounds__(256)
__global__ void ln_kernel(float* __restrict__ io, const float* __restrict__ gamma,
                          const float* __restrict__ beta) {
    __shared__ float wsum[4], wsum2[4];
    const int row = blockIdx.x;
    const int t = threadIdx.x;
    f4 x = *(const f4*)&io[(size_t)row * DM_ + t * 4];
    float s  = x[0] + x[1] + x[2] + x[3];
    float s2 = x[0]*x[0] + x[1]*x[1] + x[2]*x[2] + x[3]*x[3];
#pragma unroll
    for (int o = 32; o > 0; o >>= 1) {
        s  += __shfl_down(s, o);
        s2 += __shfl_down(s2, o);
    }
    if ((t & 63) == 0) { wsum[t >> 6] = s; wsum2[t >> 6] = s2; }
    __syncthreads();
    s  = wsum[0]  + wsum[1]  + wsum[2]  + wsum[3];
    s2 = wsum2[0] + wsum2[1] + wsum2[2] + wsum2[3];
    const float m = s * (1.f / DM_);
    const float var = s2 * (1.f / DM_) - m * m;
    const float rstd = rsqrtf(var + 1e-5f);
    f4 g  = *(const f4*)&gamma[t * 4];
    f4 bb = *(const f4*)&beta[t * 4];
    f4 o = (x - m) * rstd * g + bb;
    *(f4*)&io[(size_t)row * DM_ + t * 4] = o;
}

// ---------------------------------------------------------------------------
// Workspace layout (226 MB total):
//   [  0, 32) MB : qbuf f32  (dead after feat(q))   \__ overlaid by kv bf16 [0,64)
//   [ 32, 64) MB : kbuf f32  (dead after feat(k))   /
//   [ 64, 96) MB : vbuf f32  (attn written in-place by passC)
//   [ 96,160) MB : qp  bf16
//   [160,224) MB : kp  bf16
//   [224,226) MB : ksum f32
// ---------------------------------------------------------------------------
extern "C" void kernel_launch(void* const* d_in, const int* in_sizes, int n_in,
                              void* d_out, int out_size, void* d_ws, size_t ws_size,
                              hipStream_t stream) {
    const float* pre_q = (const float*)d_in[0];
    const float* pre_k = (const float*)d_in[1];
    const float* pre_v = (const float*)d_in[2];
    const float* wq    = (const float*)d_in[3];
    const float* wk    = (const float*)d_in[4];
    const float* wv    = (const float*)d_in[5];
    const float* wo    = (const float*)d_in[6];
    const float* gamma = (const float*)d_in[7];
    const float* beta  = (const float*)d_in[8];
    const float* omega = (const float*)d_in[9];
    const float* bvec  = (const float*)d_in[10];

    const size_t NEED = 226ull << 20;
    if (ws_size < NEED) return;  // diagnostic: finite absmax fail instead of GPU fault

    char* w = (char*)d_ws;
    float*          qbuf = (float*)(w);
    float*          kbuf = (float*)(w + (32ull << 20));
    __hip_bfloat16* kvb  = (__hip_bfloat16*)(w);            // overlays qbuf+kbuf
    float*          vbuf = (float*)(w + (64ull << 20));
    __hip_bfloat16* qp   = (__hip_bfloat16*)(w + (96ull << 20));
    __hip_bfloat16* kp   = (__hip_bfloat16*)(w + (160ull << 20));
    float*          ksum = (float*)(w + (224ull << 20));
    float*          attn = vbuf;                            // in-place (safe per-block)
    float*          outb = (float*)d_out;

    dim3 gg(DM_ / 64, M_ / 64);

    gemm_bt<<<gg, 256, 0, stream>>>(pre_q, wq, nullptr, qbuf, M_, DM_, DM_, 0);
    feat_kernel<<<M2_ / 32, 256, 0, stream>>>(qbuf, omega, bvec, qp);
    gemm_bt<<<gg, 256, 0, stream>>>(pre_k, wk, nullptr, kbuf, M_, DM_, DM_, 0);
    feat_kernel<<<M2_ / 32, 256, 0, stream>>>(kbuf, omega, bvec, kp);
    gemm_bt<<<gg, 256, 0, stream>>>(pre_v, wv, nullptr, vbuf, M_, DM_, DM_, 0);

    passA<<<dim3(NC_, H_, B_), 256, 0, stream>>>(kp, vbuf, kvb, ksum);
    passB<<<dim3(4, H_, B_), 256, 0, stream>>>(kvb, ksum);
    passC<<<dim3(NC_, H_, B_), 256, 0, stream>>>(qp, kp, vbuf, kvb, ksum, attn);

    gemm_bt<<<gg, 256, 0, stream>>>(attn, wo, pre_q, outb, M_, DM_, DM_, 1);
    ln_kernel<<<M_, 256, 0, stream>>>(outb, gamma, beta);
}

// Round 3
// 861.649 us; speedup vs baseline: 1.8026x; 1.8026x over previous
//
#include <hip/hip_runtime.h>
#include <hip/hip_bf16.h>

// Performer (ORF linear attention) + out-proj + residual + LayerNorm.
// Round 3: bf16 MFMA GEMM (m97-style 128x128 tile) for the 4 projections.
// Everything else (feat/passA/passB/passC/ln) unchanged from round 2.

typedef float f4 __attribute__((ext_vector_type(4)));
typedef __attribute__((ext_vector_type(8))) short bf16x8;
typedef __attribute__((ext_vector_type(4))) float f32x4;

#define B_  4
#define L_  2048
#define H_  16
#define D_  64
#define DM_ 1024
#define R_  256
#define C_  64
#define NC_ (L_ / C_)
#define M_  (B_ * L_)
#define M2_ (M_ * H_)

static __device__ __forceinline__ unsigned short f2bu(float x) {
    __hip_bfloat16 h = __float2bfloat16(x);
    return *(unsigned short*)&h;
}

typedef __attribute__((address_space(3))) void lds_void_t;
typedef __attribute__((address_space(1))) const void gvoid_t;
static __device__ __forceinline__ void gload16(const void* g, void* l) {
    __builtin_amdgcn_global_load_lds((gvoid_t*)g, (lds_void_t*)l, 16, 0, 0);
}

// ---------------------------------------------------------------------------
// fp32 -> bf16 cast, 4 elements/thread
// ---------------------------------------------------------------------------
__launch_bounds__(256)
__global__ void cvt_bf16(const float* __restrict__ in, unsigned short* __restrict__ out, int n4) {
    int i = blockIdx.x * 256 + threadIdx.x;
    if (i < n4) {
        f4 v = *(const f4*)&in[(size_t)i * 4];
        ushort4 o;
        o.x = f2bu(v[0]); o.y = f2bu(v[1]); o.z = f2bu(v[2]); o.w = f2bu(v[3]);
        *(ushort4*)&out[(size_t)i * 4] = o;
    }
}

// ---------------------------------------------------------------------------
// C[M,N] = A[M,K] @ B[N,K]^T  (+ optional fp32 residual add), bf16 MFMA.
// BM=BN=128, BK=32. 256 threads = 4 waves in 2x2; each wave 64x64 out =
// 4x4 fragments of 16x16x32. Staging via global_load_lds width 16.
// ---------------------------------------------------------------------------
__launch_bounds__(256)
__global__ void gemm_mfma(const unsigned short* __restrict__ A,   // [M][K] bf16
                          const unsigned short* __restrict__ Bw,  // [N][K] bf16
                          const float* __restrict__ resid,
                          float* __restrict__ C,
                          int M, int N, int K, int do_resid) {
    __shared__ unsigned short Asl[128 * 32];
    __shared__ unsigned short Bsl[128 * 32];
    const int t = threadIdx.x;
    const int lane = t & 63, w = t >> 6;
    const int wr = w >> 1, wc = w & 1;
    const int row0 = blockIdx.y * 128, col0 = blockIdx.x * 128;
    // staging chunks: thread t covers 16B chunk t and t+256 of each tile.
    const int sr0 = t >> 2, sk0 = (t & 3) * 8;
    const int lg = lane >> 4, lr = lane & 15;

    f32x4 acc[4][4] = {};
    for (int kk = 0; kk < K; kk += 32) {
        __syncthreads();  // protect LDS overwrite
        gload16(&A [(size_t)(row0 + sr0)      * K + kk + sk0], &Asl[t * 8]);
        gload16(&A [(size_t)(row0 + sr0 + 64) * K + kk + sk0], &Asl[(t + 256) * 8]);
        gload16(&Bw[(size_t)(col0 + sr0)      * K + kk + sk0], &Bsl[t * 8]);
        gload16(&Bw[(size_t)(col0 + sr0 + 64) * K + kk + sk0], &Bsl[(t + 256) * 8]);
        __syncthreads();  // compiler drains vmcnt(0) before barrier -> tile ready

        bf16x8 af[4], bfr[4];
#pragma unroll
        for (int m = 0; m < 4; ++m)
            af[m] = *(const bf16x8*)&Asl[(wr * 64 + m * 16 + lr) * 32 + lg * 8];
#pragma unroll
        for (int n = 0; n < 4; ++n)
            bfr[n] = *(const bf16x8*)&Bsl[(wc * 64 + n * 16 + lr) * 32 + lg * 8];
#pragma unroll
        for (int m = 0; m < 4; ++m)
#pragma unroll
            for (int n = 0; n < 4; ++n)
                acc[m][n] = __builtin_amdgcn_mfma_f32_16x16x32_bf16(af[m], bfr[n], acc[m][n], 0, 0, 0);
    }
    // epilogue: C/D layout col=lane&15, row=(lane>>4)*4+reg
#pragma unroll
    for (int m = 0; m < 4; ++m)
#pragma unroll
        for (int n = 0; n < 4; ++n) {
#pragma unroll
            for (int i = 0; i < 4; ++i) {
                int r  = row0 + wr * 64 + m * 16 + lg * 4 + i;
                int cc = col0 + wc * 64 + n * 16 + lr;
                size_t off = (size_t)r * N + cc;
                float v = acc[m][n][i];
                if (do_resid) v += resid[off];
                C[off] = v;
            }
        }
}

// ---------------------------------------------------------------------------
// ORF features: out[m,r] = sqrt(2/R) * cos( dot(X[m,0:64], omega[r,0:64]) + b[r] )
// ---------------------------------------------------------------------------
__launch_bounds__(256)
__global__ void feat_kernel(const float* __restrict__ X, const float* __restrict__ omega,
                            const float* __restrict__ bvec, __hip_bfloat16* __restrict__ out) {
    __shared__ __align__(16) float Xs[32][64];
    const int t  = threadIdx.x;
    const int m0 = blockIdx.x * 32;
#pragma unroll
    for (int m = 0; m < 8; ++m) {
        int flat = m * 256 + t;
        int r = flat >> 6, c = flat & 63;
        Xs[r][c] = X[(size_t)(m0 + r) * 64 + c];
    }
    f4 om[16];
#pragma unroll
    for (int j = 0; j < 16; ++j) om[j] = *(const f4*)&omega[(size_t)t * 64 + j * 4];
    const float bb = bvec[t];
    __syncthreads();

    const float scale = 0.08838834764831845f;  // sqrt(2/256)
    for (int m = 0; m < 32; ++m) {
        float s = bb;
#pragma unroll
        for (int j = 0; j < 16; ++j) {
            f4 xv = *(const f4*)&Xs[m][j * 4];
            s += om[j][0] * xv[0] + om[j][1] * xv[1] + om[j][2] * xv[2] + om[j][3] * xv[3];
        }
        out[(size_t)(m0 + m) * R_ + t] = __float2bfloat16(scale * __cosf(s));
    }
}

// ---------------------------------------------------------------------------
// passA: per (b,h,chunk): KV[r][d] = sum_l kp[l][r]*v[l][d]; ksum[r]. KV in bf16.
// ---------------------------------------------------------------------------
__launch_bounds__(256)
__global__ void passA(const __hip_bfloat16* __restrict__ kp, const float* __restrict__ v,
                      __hip_bfloat16* __restrict__ kv, float* __restrict__ ksum) {
    __shared__ __align__(16) float Vs[C_][64];
    const int c = blockIdx.x, h = blockIdx.y, bz = blockIdx.z;
    const int t = threadIdx.x;  // r
    const int l0 = c * C_;
#pragma unroll
    for (int m = 0; m < (C_ * 64) / 256; ++m) {
        int flat = m * 256 + t;
        int r = flat >> 6, cc = flat & 63;
        Vs[r][cc] = v[(size_t)(bz * L_ + l0 + r) * DM_ + h * 64 + cc];
    }
    __syncthreads();

    f4 acc[16] = {};
    float ks = 0.f;
    for (int l = 0; l < C_; ++l) {
        float kpv = __bfloat162float(kp[((size_t)(bz * L_ + l0 + l) * H_ + h) * R_ + t]);
        ks += kpv;
#pragma unroll
        for (int d4 = 0; d4 < 16; ++d4) {
            f4 vv = *(const f4*)&Vs[l][d4 * 4];
            acc[d4] += vv * kpv;
        }
    }
    const int bh = bz * H_ + h;
    size_t base = ((size_t)(bh * NC_ + c) * R_ + t) * 64;
#pragma unroll
    for (int d4 = 0; d4 < 16; ++d4) {
        ushort4 pk;
        pk.x = f2bu(acc[d4][0]); pk.y = f2bu(acc[d4][1]);
        pk.z = f2bu(acc[d4][2]); pk.w = f2bu(acc[d4][3]);
        *(ushort4*)&kv[base + d4 * 4] = pk;
    }
    ksum[(size_t)(bh * NC_ + c) * R_ + t] = ks;
}

// ---------------------------------------------------------------------------
// passB: in-place exclusive prefix over chunks (kv bf16, running sum fp32).
// ---------------------------------------------------------------------------
__launch_bounds__(256)
__global__ void passB(__hip_bfloat16* __restrict__ kv, float* __restrict__ ksum) {
    const int dg = blockIdx.x, h = blockIdx.y, bz = blockIdx.z;
    const int r = threadIdx.x;
    const int bh = bz * H_ + h;
    float run[16] = {};
    for (int c = 0; c < NC_; ++c) {
        size_t base = ((size_t)(bh * NC_ + c) * R_ + r) * 64 + dg * 16;
#pragma unroll
        for (int d = 0; d < 16; ++d) {
            float tmp = __bfloat162float(kv[base + d]);
            unsigned short u = f2bu(run[d]);
            kv[base + d] = *(__hip_bfloat16*)&u;
            run[d] += tmp;
        }
    }
    if (dg == 0) {
        float rz = 0.f;
        for (int c = 0; c < NC_; ++c) {
            size_t idx = (size_t)(bh * NC_ + c) * R_ + r;
            float tmp = ksum[idx];
            ksum[idx] = rz;
            rz += tmp;
        }
    }
}

// ---------------------------------------------------------------------------
// passC: per (b,h,chunk):
//   A = mask(QP @ KP^T); den = rowsum(A) + QP.zpref
//   out = (A @ V + QP @ Spref) / (max(den,1e-6)+1e-6)   [writes attn over v]
// ---------------------------------------------------------------------------
__launch_bounds__(256)
__global__ void passC(const __hip_bfloat16* __restrict__ qp, const __hip_bfloat16* __restrict__ kp,
                      const float* __restrict__ v, const __hip_bfloat16* __restrict__ kvpref,
                      const float* __restrict__ zpref, float* __restrict__ attn) {
    __shared__ __align__(16) float As[64][65];
    __shared__ __align__(16) float st1[32][68];
    __shared__ __align__(16) float st2[32][68];
    __shared__ __align__(16) float Vs[64][64];
    __shared__ float zs[R_];
    __shared__ float den[64];

    const int c = blockIdx.x, h = blockIdx.y, bz = blockIdx.z;
    const int t = threadIdx.x;
    const int tx = t & 15, ty = t >> 4;
    const int l0 = c * C_;
    const int bh = bz * H_ + h;

    zs[t] = zpref[(size_t)(bh * NC_ + c) * R_ + t];

    f4 accA[4] = {};
    float denz = 0.f;
    for (int s = 0; s < 8; ++s) {
#pragma unroll
        for (int m = 0; m < 8; ++m) {
            int flat = m * 256 + t;
            int i = flat >> 5, k = flat & 31;
            size_t rowb = ((size_t)(bz * L_ + l0 + i) * H_ + h) * R_ + s * 32 + k;
            st1[k][i] = __bfloat162float(qp[rowb]);
            st2[k][i] = __bfloat162float(kp[rowb]);
        }
        __syncthreads();
#pragma unroll
        for (int k2 = 0; k2 < 32; ++k2) {
            f4 a = *(const f4*)&st1[k2][ty * 4];
            f4 b = *(const f4*)&st2[k2][tx * 4];
            accA[0] += b * a[0];
            accA[1] += b * a[1];
            accA[2] += b * a[2];
            accA[3] += b * a[3];
        }
        if (t < 64) {
#pragma unroll
            for (int k2 = 0; k2 < 32; ++k2) denz += st1[k2][t] * zs[s * 32 + k2];
        }
        __syncthreads();
    }
#pragma unroll
    for (int ii = 0; ii < 4; ++ii)
#pragma unroll
        for (int jj = 0; jj < 4; ++jj) {
            int i = ty * 4 + ii, j = tx * 4 + jj;
            As[i][j] = (j <= i) ? accA[ii][jj] : 0.f;
        }
#pragma unroll
    for (int m = 0; m < 16; ++m) {
        int flat = m * 256 + t;
        int j = flat >> 6, d = flat & 63;
        Vs[j][d] = v[(size_t)(bz * L_ + l0 + j) * DM_ + h * 64 + d];
    }
    __syncthreads();

    if (t < 64) {
        float di = 0.f;
        for (int j = 0; j <= t; ++j) di += As[t][j];
        den[t] = fmaxf(denz + di, 1e-6f) + 1e-6f;
    }

    f4 accO[4] = {};
#pragma unroll
    for (int j = 0; j < 64; ++j) {
        f4 vv = *(const f4*)&Vs[j][tx * 4];
        accO[0] += vv * As[ty * 4 + 0][j];
        accO[1] += vv * As[ty * 4 + 1][j];
        accO[2] += vv * As[ty * 4 + 2][j];
        accO[3] += vv * As[ty * 4 + 3][j];
    }
    for (int s = 0; s < 8; ++s) {
#pragma unroll
        for (int m = 0; m < 8; ++m) {
            int flat = m * 256 + t;
            int i = flat >> 5, k = flat & 31;
            st1[k][i] = __bfloat162float(qp[((size_t)(bz * L_ + l0 + i) * H_ + h) * R_ + s * 32 + k]);
        }
#pragma unroll
        for (int m = 0; m < 8; ++m) {
            int flat = m * 256 + t;
            int k = flat >> 6, d = flat & 63;
            st2[k][d] = __bfloat162float(kvpref[((size_t)(bh * NC_ + c) * R_ + s * 32 + k) * 64 + d]);
        }
        __syncthreads();
#pragma unroll
        for (int k2 = 0; k2 < 32; ++k2) {
            f4 qv = *(const f4*)&st1[k2][ty * 4];
            f4 sv = *(const f4*)&st2[k2][tx * 4];
            accO[0] += sv * qv[0];
            accO[1] += sv * qv[1];
            accO[2] += sv * qv[2];
            accO[3] += sv * qv[3];
        }
        __syncthreads();
    }
#pragma unroll
    for (int ii = 0; ii < 4; ++ii) {
        float inv = 1.f / den[ty * 4 + ii];
        f4 o = accO[ii] * inv;
        *(f4*)&attn[(size_t)(bz * L_ + l0 + ty * 4 + ii) * DM_ + h * 64 + tx * 4] = o;
    }
}

// ---------------------------------------------------------------------------
// In-place row LayerNorm over last dim (1024), eps=1e-5.
// ---------------------------------------------------------------------------
__launch_bounds__(256)
__global__ void ln_kernel(float* __restrict__ io, const float* __restrict__ gamma,
                          const float* __restrict__ beta) {
    __shared__ float wsum[4], wsum2[4];
    const int row = blockIdx.x;
    const int t = threadIdx.x;
    f4 x = *(const f4*)&io[(size_t)row * DM_ + t * 4];
    float s  = x[0] + x[1] + x[2] + x[3];
    float s2 = x[0]*x[0] + x[1]*x[1] + x[2]*x[2] + x[3]*x[3];
#pragma unroll
    for (int o = 32; o > 0; o >>= 1) {
        s  += __shfl_down(s, o);
        s2 += __shfl_down(s2, o);
    }
    if ((t & 63) == 0) { wsum[t >> 6] = s; wsum2[t >> 6] = s2; }
    __syncthreads();
    s  = wsum[0]  + wsum[1]  + wsum[2]  + wsum[3];
    s2 = wsum2[0] + wsum2[1] + wsum2[2] + wsum2[3];
    const float m = s * (1.f / DM_);
    const float var = s2 * (1.f / DM_) - m * m;
    const float rstd = rsqrtf(var + 1e-5f);
    f4 g  = *(const f4*)&gamma[t * 4];
    f4 bb = *(const f4*)&beta[t * 4];
    f4 o = (x - m) * rstd * g + bb;
    *(f4*)&io[(size_t)row * DM_ + t * 4] = o;
}

// ---------------------------------------------------------------------------
// Workspace (226 MB), with staged aliasing:
//   [  0, 32) qbuf f32     | later: abuf_v bf16 [0,16) + wv_bf [16,18) | kv bf16 [0,64)
//                          | after passC: abuf_o bf16 [0,16) + wo_bf [16,18)
//   [ 32, 64) kbuf f32     | (kv tail)
//   [ 64, 96) vbuf f32 (passC writes attn in place)
//       during gemm q/k: abuf bf16 [64,80) + w_bf [80,82)
//   [ 96,160) qp bf16
//   [160,224) kp bf16
//   [224,226) ksum f32
// ---------------------------------------------------------------------------
extern "C" void kernel_launch(void* const* d_in, const int* in_sizes, int n_in,
                              void* d_out, int out_size, void* d_ws, size_t ws_size,
                              hipStream_t stream) {
    const float* pre_q = (const float*)d_in[0];
    const float* pre_k = (const float*)d_in[1];
    const float* pre_v = (const float*)d_in[2];
    const float* wq    = (const float*)d_in[3];
    const float* wk    = (const float*)d_in[4];
    const float* wv    = (const float*)d_in[5];
    const float* wo    = (const float*)d_in[6];
    const float* gamma = (const float*)d_in[7];
    const float* beta  = (const float*)d_in[8];
    const float* omega = (const float*)d_in[9];
    const float* bvec  = (const float*)d_in[10];

    const size_t NEED = 226ull << 20;
    if (ws_size < NEED) return;

    char* w = (char*)d_ws;
    float*          qbuf  = (float*)(w);
    float*          kbuf  = (float*)(w + (32ull << 20));
    __hip_bfloat16* kvb   = (__hip_bfloat16*)(w);
    float*          vbuf  = (float*)(w + (64ull << 20));
    unsigned short* abqk  = (unsigned short*)(w + (64ull << 20));   // 16MB, q/k staging
    unsigned short* wbqk  = (unsigned short*)(w + (80ull << 20));   // 2MB
    unsigned short* abv   = (unsigned short*)(w);                   // 16MB, v staging
    unsigned short* wbv   = (unsigned short*)(w + (16ull << 20));   // 2MB
    unsigned short* abo   = (unsigned short*)(w);                   // 16MB, attn staging
    unsigned short* wbo   = (unsigned short*)(w + (16ull << 20));   // 2MB
    __hip_bfloat16* qp    = (__hip_bfloat16*)(w + (96ull << 20));
    __hip_bfloat16* kp    = (__hip_bfloat16*)(w + (160ull << 20));
    float*          ksum  = (float*)(w + (224ull << 20));
    float*          attn  = vbuf;
    float*          outb  = (float*)d_out;

    const int n4_big = M_ * DM_ / 4;   // 2M vec4
    const int n4_w   = DM_ * DM_ / 4;  // 256K vec4
    dim3 gg(DM_ / 128, M_ / 128);      // (8, 64)

    // Q
    cvt_bf16<<<(n4_big + 255) / 256, 256, 0, stream>>>(pre_q, abqk, n4_big);
    cvt_bf16<<<(n4_w + 255) / 256, 256, 0, stream>>>(wq, wbqk, n4_w);
    gemm_mfma<<<gg, 256, 0, stream>>>(abqk, wbqk, nullptr, qbuf, M_, DM_, DM_, 0);
    feat_kernel<<<M2_ / 32, 256, 0, stream>>>(qbuf, omega, bvec, qp);
    // K
    cvt_bf16<<<(n4_big + 255) / 256, 256, 0, stream>>>(pre_k, abqk, n4_big);
    cvt_bf16<<<(n4_w + 255) / 256, 256, 0, stream>>>(wk, wbqk, n4_w);
    gemm_mfma<<<gg, 256, 0, stream>>>(abqk, wbqk, nullptr, kbuf, M_, DM_, DM_, 0);
    feat_kernel<<<M2_ / 32, 256, 0, stream>>>(kbuf, omega, bvec, kp);
    // V (staging in [0,18) — qbuf dead after feat(q))
    cvt_bf16<<<(n4_big + 255) / 256, 256, 0, stream>>>(pre_v, abv, n4_big);
    cvt_bf16<<<(n4_w + 255) / 256, 256, 0, stream>>>(wv, wbv, n4_w);
    gemm_mfma<<<gg, 256, 0, stream>>>(abv, wbv, nullptr, vbuf, M_, DM_, DM_, 0);

    passA<<<dim3(NC_, H_, B_), 256, 0, stream>>>(kp, vbuf, kvb, ksum);
    passB<<<dim3(4, H_, B_), 256, 0, stream>>>(kvb, ksum);
    passC<<<dim3(NC_, H_, B_), 256, 0, stream>>>(qp, kp, vbuf, kvb, ksum, attn);

    // out-proj + residual (kv dead -> reuse [0,18) for attn/wo bf16)
    cvt_bf16<<<(n4_big + 255) / 256, 256, 0, stream>>>(attn, abo, n4_big);
    cvt_bf16<<<(n4_w + 255) / 256, 256, 0, stream>>>(wo, wbo, n4_w);
    gemm_mfma<<<gg, 256, 0, stream>>>(abo, wbo, pre_q, outb, M_, DM_, DM_, 1);
    ln_kernel<<<M_, 256, 0, stream>>>(outb, gamma, beta);
}

// Round 4
// 528.782 us; speedup vs baseline: 2.9374x; 1.6295x over previous
//
#include <hip/hip_runtime.h>
#include <hip/hip_bf16.h>

// Performer (ORF linear attention) + out-proj + residual + LayerNorm.
// Round 4: MFMA passC (scores+PV+fused den) and MFMA passA; chain-passB.

typedef float f4 __attribute__((ext_vector_type(4)));
typedef __attribute__((ext_vector_type(8))) short bf16x8;
typedef __attribute__((ext_vector_type(4))) float f32x4;
typedef unsigned short u16x4 __attribute__((ext_vector_type(4)));
typedef unsigned short u16x8 __attribute__((ext_vector_type(8)));

#define B_  4
#define L_  2048
#define H_  16
#define D_  64
#define DM_ 1024
#define R_  256
#define C_  64
#define NC_ (L_ / C_)
#define M_  (B_ * L_)
#define M2_ (M_ * H_)

static __device__ __forceinline__ unsigned short f2bu(float x) {
    __hip_bfloat16 h = __float2bfloat16(x);
    return *(unsigned short*)&h;
}
static __device__ __forceinline__ float bu2f(unsigned short u) {
    unsigned int x = ((unsigned int)u) << 16;
    union { unsigned int i; float f; } c; c.i = x; return c.f;
}

typedef __attribute__((address_space(3))) void lds_void_t;
typedef __attribute__((address_space(1))) const void gvoid_t;
static __device__ __forceinline__ void gload16(const void* g, void* l) {
    __builtin_amdgcn_global_load_lds((gvoid_t*)g, (lds_void_t*)l, 16, 0, 0);
}

// ---------------------------------------------------------------------------
// fp32 -> bf16 cast, 4 elements/thread
// ---------------------------------------------------------------------------
__launch_bounds__(256)
__global__ void cvt_bf16(const float* __restrict__ in, unsigned short* __restrict__ out, int n4) {
    int i = blockIdx.x * 256 + threadIdx.x;
    if (i < n4) {
        f4 v = *(const f4*)&in[(size_t)i * 4];
        ushort4 o;
        o.x = f2bu(v[0]); o.y = f2bu(v[1]); o.z = f2bu(v[2]); o.w = f2bu(v[3]);
        *(ushort4*)&out[(size_t)i * 4] = o;
    }
}

// ---------------------------------------------------------------------------
// C[M,N] = A[M,K] @ B[N,K]^T (+ optional fp32 residual), bf16 MFMA, 128x128.
// ---------------------------------------------------------------------------
__launch_bounds__(256)
__global__ void gemm_mfma(const unsigned short* __restrict__ A,
                          const unsigned short* __restrict__ Bw,
                          const float* __restrict__ resid,
                          float* __restrict__ C,
                          int M, int N, int K, int do_resid) {
    __shared__ unsigned short Asl[128 * 32];
    __shared__ unsigned short Bsl[128 * 32];
    const int t = threadIdx.x;
    const int lane = t & 63, w = t >> 6;
    const int wr = w >> 1, wc = w & 1;
    const int row0 = blockIdx.y * 128, col0 = blockIdx.x * 128;
    const int sr0 = t >> 2, sk0 = (t & 3) * 8;
    const int lg = lane >> 4, lr = lane & 15;

    f32x4 acc[4][4] = {};
    for (int kk = 0; kk < K; kk += 32) {
        __syncthreads();
        gload16(&A [(size_t)(row0 + sr0)      * K + kk + sk0], &Asl[t * 8]);
        gload16(&A [(size_t)(row0 + sr0 + 64) * K + kk + sk0], &Asl[(t + 256) * 8]);
        gload16(&Bw[(size_t)(col0 + sr0)      * K + kk + sk0], &Bsl[t * 8]);
        gload16(&Bw[(size_t)(col0 + sr0 + 64) * K + kk + sk0], &Bsl[(t + 256) * 8]);
        __syncthreads();

        bf16x8 af[4], bfr[4];
#pragma unroll
        for (int m = 0; m < 4; ++m)
            af[m] = *(const bf16x8*)&Asl[(wr * 64 + m * 16 + lr) * 32 + lg * 8];
#pragma unroll
        for (int n = 0; n < 4; ++n)
            bfr[n] = *(const bf16x8*)&Bsl[(wc * 64 + n * 16 + lr) * 32 + lg * 8];
#pragma unroll
        for (int m = 0; m < 4; ++m)
#pragma unroll
            for (int n = 0; n < 4; ++n)
                acc[m][n] = __builtin_amdgcn_mfma_f32_16x16x32_bf16(af[m], bfr[n], acc[m][n], 0, 0, 0);
    }
#pragma unroll
    for (int m = 0; m < 4; ++m)
#pragma unroll
        for (int n = 0; n < 4; ++n) {
#pragma unroll
            for (int i = 0; i < 4; ++i) {
                int r  = row0 + wr * 64 + m * 16 + lg * 4 + i;
                int cc = col0 + wc * 64 + n * 16 + lr;
                size_t off = (size_t)r * N + cc;
                float v = acc[m][n][i];
                if (do_resid) v += resid[off];
                C[off] = v;
            }
        }
}

// ---------------------------------------------------------------------------
// ORF features
// ---------------------------------------------------------------------------
__launch_bounds__(256)
__global__ void feat_kernel(const float* __restrict__ X, const float* __restrict__ omega,
                            const float* __restrict__ bvec, __hip_bfloat16* __restrict__ out) {
    __shared__ __align__(16) float Xs[32][64];
    const int t  = threadIdx.x;
    const int m0 = blockIdx.x * 32;
#pragma unroll
    for (int m = 0; m < 8; ++m) {
        int flat = m * 256 + t;
        int r = flat >> 6, c = flat & 63;
        Xs[r][c] = X[(size_t)(m0 + r) * 64 + c];
    }
    f4 om[16];
#pragma unroll
    for (int j = 0; j < 16; ++j) om[j] = *(const f4*)&omega[(size_t)t * 64 + j * 4];
    const float bb = bvec[t];
    __syncthreads();

    const float scale = 0.08838834764831845f;  // sqrt(2/256)
    for (int m = 0; m < 32; ++m) {
        float s = bb;
#pragma unroll
        for (int j = 0; j < 16; ++j) {
            f4 xv = *(const f4*)&Xs[m][j * 4];
            s += om[j][0] * xv[0] + om[j][1] * xv[1] + om[j][2] * xv[2] + om[j][3] * xv[3];
        }
        out[(size_t)(m0 + m) * R_ + t] = __float2bfloat16(scale * __cosf(s));
    }
}

// ---------------------------------------------------------------------------
// passA (MFMA): per (c,h,b): KV[r][d] = sum_l kp[l][r]*v[l][d]  (bf16 out),
// ksum[r] = sum_l kp[l][r].  A-op = V^T [d][l], B-op = KP^T [r][l].
// ---------------------------------------------------------------------------
__launch_bounds__(256)
__global__ void passA_mfma(const unsigned short* __restrict__ kp, const float* __restrict__ v,
                           unsigned short* __restrict__ kv, float* __restrict__ ksum) {
    __shared__ __align__(16) unsigned short KPt[256][72];  // [r][l]
    __shared__ __align__(16) unsigned short Vt[64][72];    // [d][l]
    const int c = blockIdx.x, h = blockIdx.y, bz = blockIdx.z;
    const int t = threadIdx.x;
    const int lane = t & 63, w = t >> 6;
    const int lg = lane >> 4, lr = lane & 15;
    const int l0 = c * C_;
    const int bh = bz * H_ + h;

    // stage KP^T: thread reads 4 rows (l) x 16 cols (r), writes transposed u16x4
    {
        const int l4 = (t & 15) * 4, rs = (t >> 4) * 16;
        u16x8 row[4][2];
#pragma unroll
        for (int i = 0; i < 4; ++i) {
            const unsigned short* src = &kp[((size_t)(bz * L_ + l0 + l4 + i) * H_ + h) * R_ + rs];
            row[i][0] = *(const u16x8*)src;
            row[i][1] = *(const u16x8*)(src + 8);
        }
#pragma unroll
        for (int q = 0; q < 16; ++q) {
            u16x4 pk = { row[0][q >> 3][q & 7], row[1][q >> 3][q & 7],
                         row[2][q >> 3][q & 7], row[3][q >> 3][q & 7] };
            *(u16x4*)&KPt[rs + q][l4] = pk;
        }
    }
    // stage V^T (fp32 -> bf16)
    {
        const int d4 = (t & 15) * 4, ls = (t >> 4) * 4;
        f4 x[4];
#pragma unroll
        for (int i = 0; i < 4; ++i)
            x[i] = *(const f4*)&v[(size_t)(bz * L_ + l0 + ls + i) * DM_ + h * 64 + d4];
#pragma unroll
        for (int q = 0; q < 4; ++q) {
            u16x4 pk = { f2bu(x[0][q]), f2bu(x[1][q]), f2bu(x[2][q]), f2bu(x[3][q]) };
            *(u16x4*)&Vt[d4 + q][ls] = pk;
        }
    }
    __syncthreads();

    f32x4 acc[4][4] = {};
#pragma unroll
    for (int ks = 0; ks < 2; ++ks) {
        bf16x8 af[4], bfr[4];
#pragma unroll
        for (int m = 0; m < 4; ++m)
            af[m] = *(const bf16x8*)&Vt[16 * m + lr][ks * 32 + lg * 8];
#pragma unroll
        for (int n = 0; n < 4; ++n)
            bfr[n] = *(const bf16x8*)&KPt[64 * w + 16 * n + lr][ks * 32 + lg * 8];
#pragma unroll
        for (int m = 0; m < 4; ++m)
#pragma unroll
            for (int n = 0; n < 4; ++n)
                acc[m][n] = __builtin_amdgcn_mfma_f32_16x16x32_bf16(af[m], bfr[n], acc[m][n], 0, 0, 0);
    }
    // write KV[r][d] bf16, ushort4-packed over d
    size_t kvbase = ((size_t)(bh * NC_ + c)) * R_ * 64;
#pragma unroll
    for (int m = 0; m < 4; ++m)
#pragma unroll
        for (int n = 0; n < 4; ++n) {
            int r = 64 * w + 16 * n + lr;
            int d = 16 * m + lg * 4;
            u16x4 pk = { f2bu(acc[m][n][0]), f2bu(acc[m][n][1]),
                         f2bu(acc[m][n][2]), f2bu(acc[m][n][3]) };
            *(u16x4*)&kv[kvbase + (size_t)r * 64 + d] = pk;
        }
    // ksum[r] from KPt row t
    {
        float s = 0.f;
#pragma unroll
        for (int j = 0; j < 8; ++j) {
            u16x8 vv = *(const u16x8*)&KPt[t][j * 8];
#pragma unroll
            for (int q = 0; q < 8; ++q) s += bu2f(vv[q]);
        }
        ksum[((size_t)(bh * NC_ + c)) * R_ + t] = s;
    }
}

// ---------------------------------------------------------------------------
// passB: exclusive prefix over chunks; one (r,d) chain per thread.
// grid (64, H, B): block bx covers r in [4bx, 4bx+4), threads: d = t&63.
// ---------------------------------------------------------------------------
__launch_bounds__(256)
__global__ void passB_chain(unsigned short* __restrict__ kv, float* __restrict__ ksum) {
    const int bx = blockIdx.x, h = blockIdx.y, bz = blockIdx.z;
    const int t = threadIdx.x;
    const int bh = bz * H_ + h;
    const int r = bx * 4 + (t >> 6);
    const int d = t & 63;
    size_t base = ((size_t)bh * NC_ * R_ + r) * 64 + d;
    const size_t cstride = (size_t)R_ * 64;
    float run = 0.f;
    for (int c = 0; c < NC_; ++c) {
        size_t idx = base + (size_t)c * cstride;
        float tmp = bu2f(kv[idx]);
        kv[idx] = f2bu(run);
        run += tmp;
    }
    if (bx == 0) {
        float rz = 0.f;
        for (int c = 0; c < NC_; ++c) {
            size_t idx = ((size_t)bh * NC_ + c) * R_ + t;
            float tmp = ksum[idx];
            ksum[idx] = rz;
            rz += tmp;
        }
    }
}

// ---------------------------------------------------------------------------
// passC (MFMA): per (c,h,b):
//   A = mask(QP @ KP^T) -> bf16 LDS
//   [num | den] = A @ [V^T | ones] + QP @ [Spref^T | zpref]   (den = col 64)
//   out = num / (max(den,1e-6)+1e-6)    (writes attn over v, staged first)
// ---------------------------------------------------------------------------
__launch_bounds__(256)
__global__ void passC_mfma(const unsigned short* __restrict__ qp, const unsigned short* __restrict__ kp,
                           const float* __restrict__ v, const unsigned short* __restrict__ kvpref,
                           const float* __restrict__ zpref, float* __restrict__ attn) {
    __shared__ __align__(16) unsigned short SprefT[80][264];  // [d][r], row64=zpref, 65..79=0
    __shared__ __align__(16) unsigned short Vt[80][72];       // [d][l], row64=ones, 65..79=0
    __shared__ __align__(16) unsigned short As[64][72];       // masked scores [i][j]

    const int c = blockIdx.x, h = blockIdx.y, bz = blockIdx.z;
    const int t = threadIdx.x;
    const int lane = t & 63, w = t >> 6;
    const int lg = lane >> 4, lr = lane & 15;
    const int l0 = c * C_;
    const int bh = bz * H_ + h;

    // ---- stage Spref^T from kv [r][d] ----
    {
        const int r4 = (t & 63) * 4, ds = (t >> 6) * 16;
        u16x8 row[4][2];
#pragma unroll
        for (int i = 0; i < 4; ++i) {
            const unsigned short* src = &kvpref[(((size_t)(bh * NC_ + c)) * R_ + r4 + i) * 64 + ds];
            row[i][0] = *(const u16x8*)src;
            row[i][1] = *(const u16x8*)(src + 8);
        }
#pragma unroll
        for (int q = 0; q < 16; ++q) {
            u16x4 pk = { row[0][q >> 3][q & 7], row[1][q >> 3][q & 7],
                         row[2][q >> 3][q & 7], row[3][q >> 3][q & 7] };
            *(u16x4*)&SprefT[ds + q][r4] = pk;
        }
    }
    if (t < 32) {  // row 64 = zpref (f32 -> bf16)
        f4 z0 = *(const f4*)&zpref[((size_t)(bh * NC_ + c)) * R_ + t * 8];
        f4 z1 = *(const f4*)&zpref[((size_t)(bh * NC_ + c)) * R_ + t * 8 + 4];
        u16x8 pk = { f2bu(z0[0]), f2bu(z0[1]), f2bu(z0[2]), f2bu(z0[3]),
                     f2bu(z1[0]), f2bu(z1[1]), f2bu(z1[2]), f2bu(z1[3]) };
        *(u16x8*)&SprefT[64][t * 8] = pk;
    }
    for (int i = t; i < 15 * 264; i += 256) SprefT[65 + i / 264][i % 264] = 0;

    // ---- stage V^T (fp32 -> bf16), ones row, zero rows ----
    {
        const int d4 = (t & 15) * 4, ls = (t >> 4) * 4;
        f4 x[4];
#pragma unroll
        for (int i = 0; i < 4; ++i)
            x[i] = *(const f4*)&v[(size_t)(bz * L_ + l0 + ls + i) * DM_ + h * 64 + d4];
#pragma unroll
        for (int q = 0; q < 4; ++q) {
            u16x4 pk = { f2bu(x[0][q]), f2bu(x[1][q]), f2bu(x[2][q]), f2bu(x[3][q]) };
            *(u16x4*)&Vt[d4 + q][ls] = pk;
        }
    }
    if (t < 16) {
        u16x4 ones = { 0x3F80, 0x3F80, 0x3F80, 0x3F80 };
        *(u16x4*)&Vt[64][t * 4] = ones;
    }
    for (int i = t; i < 15 * 72; i += 256) Vt[65 + i / 72][i % 72] = 0;

    // ---- scores: wave w rows 16w..16w+15 x 64 keys, K=256 ----
    const size_t qrow = ((size_t)(bz * L_ + l0 + 16 * w + lr) * H_ + h) * R_;
    f32x4 sacc[4] = {};
#pragma unroll
    for (int ks = 0; ks < 8; ++ks) {
        bf16x8 aq = *(const bf16x8*)&qp[qrow + ks * 32 + lg * 8];
#pragma unroll
        for (int n = 0; n < 4; ++n) {
            bf16x8 bk = *(const bf16x8*)&kp[((size_t)(bz * L_ + l0 + 16 * n + lr) * H_ + h) * R_ + ks * 32 + lg * 8];
            sacc[n] = __builtin_amdgcn_mfma_f32_16x16x32_bf16(aq, bk, sacc[n], 0, 0, 0);
        }
    }
    // mask (j<=i) and write As bf16
#pragma unroll
    for (int n = 0; n < 4; ++n)
#pragma unroll
        for (int ii = 0; ii < 4; ++ii) {
            int i_loc = 16 * w + lg * 4 + ii;
            int j_loc = 16 * n + lr;
            As[i_loc][j_loc] = (j_loc <= i_loc) ? f2bu(sacc[n][ii]) : (unsigned short)0;
        }
    __syncthreads();

    // ---- PV: oacc[n] n=0..3 = num cols, n=4 col 64 = den ----
    f32x4 oacc[5] = {};
#pragma unroll
    for (int ks = 0; ks < 2; ++ks) {
        bf16x8 aa = *(const bf16x8*)&As[16 * w + lr][ks * 32 + lg * 8];
#pragma unroll
        for (int n = 0; n < 5; ++n) {
            bf16x8 bv = *(const bf16x8*)&Vt[16 * n + lr][ks * 32 + lg * 8];
            oacc[n] = __builtin_amdgcn_mfma_f32_16x16x32_bf16(aa, bv, oacc[n], 0, 0, 0);
        }
    }
#pragma unroll
    for (int ks = 0; ks < 8; ++ks) {
        bf16x8 aq = *(const bf16x8*)&qp[qrow + ks * 32 + lg * 8];
#pragma unroll
        for (int n = 0; n < 5; ++n) {
            bf16x8 bs = *(const bf16x8*)&SprefT[16 * n + lr][ks * 32 + lg * 8];
            oacc[n] = __builtin_amdgcn_mfma_f32_16x16x32_bf16(aq, bs, oacc[n], 0, 0, 0);
        }
    }
    // ---- epilogue ----
#pragma unroll
    for (int ii = 0; ii < 4; ++ii) {
        float den = __shfl(oacc[4][ii], lane & 48, 64);  // col 64 lives at lr==0
        float inv = 1.f / (fmaxf(den, 1e-6f) + 1e-6f);
#pragma unroll
        for (int n = 0; n < 4; ++n)
            attn[(size_t)(bz * L_ + l0 + 16 * w + lg * 4 + ii) * DM_ + h * 64 + 16 * n + lr] = oacc[n][ii] * inv;
    }
}

// ---------------------------------------------------------------------------
// In-place row LayerNorm over last dim (1024), eps=1e-5.
// ---------------------------------------------------------------------------
__launch_bounds__(256)
__global__ void ln_kernel(float* __restrict__ io, const float* __restrict__ gamma,
                          const float* __restrict__ beta) {
    __shared__ float wsum[4], wsum2[4];
    const int row = blockIdx.x;
    const int t = threadIdx.x;
    f4 x = *(const f4*)&io[(size_t)row * DM_ + t * 4];
    float s  = x[0] + x[1] + x[2] + x[3];
    float s2 = x[0]*x[0] + x[1]*x[1] + x[2]*x[2] + x[3]*x[3];
#pragma unroll
    for (int o = 32; o > 0; o >>= 1) {
        s  += __shfl_down(s, o);
        s2 += __shfl_down(s2, o);
    }
    if ((t & 63) == 0) { wsum[t >> 6] = s; wsum2[t >> 6] = s2; }
    __syncthreads();
    s  = wsum[0]  + wsum[1]  + wsum[2]  + wsum[3];
    s2 = wsum2[0] + wsum2[1] + wsum2[2] + wsum2[3];
    const float m = s * (1.f / DM_);
    const float var = s2 * (1.f / DM_) - m * m;
    const float rstd = rsqrtf(var + 1e-5f);
    f4 g  = *(const f4*)&gamma[t * 4];
    f4 bb = *(const f4*)&beta[t * 4];
    f4 o = (x - m) * rstd * g + bb;
    *(f4*)&io[(size_t)row * DM_ + t * 4] = o;
}

// ---------------------------------------------------------------------------
// Workspace (226 MB):
//   [  0, 64) kv bf16 (overlays qbuf/kbuf f32 [0,32)/[32,64))
//   [ 64, 96) vbuf f32 (attn in-place) | q/k bf16 staging [64,80)+[80,82)
//   [ 96,160) qp bf16 | [160,224) kp bf16 | [224,226) ksum f32
// ---------------------------------------------------------------------------
extern "C" void kernel_launch(void* const* d_in, const int* in_sizes, int n_in,
                              void* d_out, int out_size, void* d_ws, size_t ws_size,
                              hipStream_t stream) {
    const float* pre_q = (const float*)d_in[0];
    const float* pre_k = (const float*)d_in[1];
    const float* pre_v = (const float*)d_in[2];
    const float* wq    = (const float*)d_in[3];
    const float* wk    = (const float*)d_in[4];
    const float* wv    = (const float*)d_in[5];
    const float* wo    = (const float*)d_in[6];
    const float* gamma = (const float*)d_in[7];
    const float* beta  = (const float*)d_in[8];
    const float* omega = (const float*)d_in[9];
    const float* bvec  = (const float*)d_in[10];

    const size_t NEED = 226ull << 20;
    if (ws_size < NEED) return;

    char* w = (char*)d_ws;
    float*          qbuf  = (float*)(w);
    float*          kbuf  = (float*)(w + (32ull << 20));
    unsigned short* kvb   = (unsigned short*)(w);
    float*          vbuf  = (float*)(w + (64ull << 20));
    unsigned short* abqk  = (unsigned short*)(w + (64ull << 20));
    unsigned short* wbqk  = (unsigned short*)(w + (80ull << 20));
    unsigned short* abv   = (unsigned short*)(w);
    unsigned short* wbv   = (unsigned short*)(w + (16ull << 20));
    unsigned short* abo   = (unsigned short*)(w);
    unsigned short* wbo   = (unsigned short*)(w + (16ull << 20));
    unsigned short* qp    = (unsigned short*)(w + (96ull << 20));
    unsigned short* kp    = (unsigned short*)(w + (160ull << 20));
    float*          ksum  = (float*)(w + (224ull << 20));
    float*          attn  = vbuf;
    float*          outb  = (float*)d_out;

    const int n4_big = M_ * DM_ / 4;
    const int n4_w   = DM_ * DM_ / 4;
    dim3 gg(DM_ / 128, M_ / 128);

    cvt_bf16<<<(n4_big + 255) / 256, 256, 0, stream>>>(pre_q, abqk, n4_big);
    cvt_bf16<<<(n4_w + 255) / 256, 256, 0, stream>>>(wq, wbqk, n4_w);
    gemm_mfma<<<gg, 256, 0, stream>>>(abqk, wbqk, nullptr, qbuf, M_, DM_, DM_, 0);
    feat_kernel<<<M2_ / 32, 256, 0, stream>>>(qbuf, omega, bvec, (__hip_bfloat16*)qp);

    cvt_bf16<<<(n4_big + 255) / 256, 256, 0, stream>>>(pre_k, abqk, n4_big);
    cvt_bf16<<<(n4_w + 255) / 256, 256, 0, stream>>>(wk, wbqk, n4_w);
    gemm_mfma<<<gg, 256, 0, stream>>>(abqk, wbqk, nullptr, kbuf, M_, DM_, DM_, 0);
    feat_kernel<<<M2_ / 32, 256, 0, stream>>>(kbuf, omega, bvec, (__hip_bfloat16*)kp);

    cvt_bf16<<<(n4_big + 255) / 256, 256, 0, stream>>>(pre_v, abv, n4_big);
    cvt_bf16<<<(n4_w + 255) / 256, 256, 0, stream>>>(wv, wbv, n4_w);
    gemm_mfma<<<gg, 256, 0, stream>>>(abv, wbv, nullptr, vbuf, M_, DM_, DM_, 0);

    passA_mfma<<<dim3(NC_, H_, B_), 256, 0, stream>>>(kp, vbuf, kvb, ksum);
    passB_chain<<<dim3(64, H_, B_), 256, 0, stream>>>(kvb, ksum);
    passC_mfma<<<dim3(NC_, H_, B_), 256, 0, stream>>>(qp, kp, vbuf, kvb, ksum, attn);

    cvt_bf16<<<(n4_big + 255) / 256, 256, 0, stream>>>(attn, abo, n4_big);
    cvt_bf16<<<(n4_w + 255) / 256, 256, 0, stream>>>(wo, wbo, n4_w);
    gemm_mfma<<<gg, 256, 0, stream>>>(abo, wbo, pre_q, outb, M_, DM_, DM_, 1);
    ln_kernel<<<M_, 256, 0, stream>>>(outb, gamma, beta);
}

// Round 5
// 398.337 us; speedup vs baseline: 3.8993x; 1.3275x over previous
//
#include <hip/hip_runtime.h>
#include <hip/hip_bf16.h>

// Performer (ORF linear attention) + out-proj + residual + LayerNorm.
// Round 5: MFMA feature map; bf16 end-to-end through the attention middle.

typedef float f4 __attribute__((ext_vector_type(4)));
typedef __attribute__((ext_vector_type(8))) short bf16x8;
typedef __attribute__((ext_vector_type(4))) float f32x4;
typedef unsigned short u16x4 __attribute__((ext_vector_type(4)));
typedef unsigned short u16x8 __attribute__((ext_vector_type(8)));

#define B_  4
#define L_  2048
#define H_  16
#define D_  64
#define DM_ 1024
#define R_  256
#define C_  64
#define NC_ (L_ / C_)
#define M_  (B_ * L_)
#define M2_ (M_ * H_)

static __device__ __forceinline__ unsigned short f2bu(float x) {
    __hip_bfloat16 h = __float2bfloat16(x);
    return *(unsigned short*)&h;
}
static __device__ __forceinline__ float bu2f(unsigned short u) {
    union { unsigned int i; float f; } c; c.i = ((unsigned int)u) << 16; return c.f;
}

typedef __attribute__((address_space(3))) void lds_void_t;
typedef __attribute__((address_space(1))) const void gvoid_t;
static __device__ __forceinline__ void gload16(const void* g, void* l) {
    __builtin_amdgcn_global_load_lds((gvoid_t*)g, (lds_void_t*)l, 16, 0, 0);
}

// ---------------------------------------------------------------------------
// fp32 -> bf16 cast, 4 elements/thread
// ---------------------------------------------------------------------------
__launch_bounds__(256)
__global__ void cvt_bf16(const float* __restrict__ in, unsigned short* __restrict__ out, int n4) {
    int i = blockIdx.x * 256 + threadIdx.x;
    if (i < n4) {
        f4 v = *(const f4*)&in[(size_t)i * 4];
        ushort4 o;
        o.x = f2bu(v[0]); o.y = f2bu(v[1]); o.z = f2bu(v[2]); o.w = f2bu(v[3]);
        *(ushort4*)&out[(size_t)i * 4] = o;
    }
}

// ---------------------------------------------------------------------------
// C[M,N] = A[M,K] @ B[N,K]^T, bf16 MFMA, 128x128 tile.
// mode 0: fp32 out; mode 1: fp32 out + fp32 resid; mode 2: bf16 out.
// ---------------------------------------------------------------------------
__launch_bounds__(256)
__global__ void gemm_mfma(const unsigned short* __restrict__ A,
                          const unsigned short* __restrict__ Bw,
                          const float* __restrict__ resid,
                          float* __restrict__ Cf, unsigned short* __restrict__ Cb,
                          int M, int N, int K, int mode) {
    __shared__ unsigned short Asl[128 * 32];
    __shared__ unsigned short Bsl[128 * 32];
    const int t = threadIdx.x;
    const int lane = t & 63, w = t >> 6;
    const int wr = w >> 1, wc = w & 1;
    const int row0 = blockIdx.y * 128, col0 = blockIdx.x * 128;
    const int sr0 = t >> 2, sk0 = (t & 3) * 8;
    const int lg = lane >> 4, lr = lane & 15;

    f32x4 acc[4][4] = {};
    for (int kk = 0; kk < K; kk += 32) {
        __syncthreads();
        gload16(&A [(size_t)(row0 + sr0)      * K + kk + sk0], &Asl[t * 8]);
        gload16(&A [(size_t)(row0 + sr0 + 64) * K + kk + sk0], &Asl[(t + 256) * 8]);
        gload16(&Bw[(size_t)(col0 + sr0)      * K + kk + sk0], &Bsl[t * 8]);
        gload16(&Bw[(size_t)(col0 + sr0 + 64) * K + kk + sk0], &Bsl[(t + 256) * 8]);
        __syncthreads();

        bf16x8 af[4], bfr[4];
#pragma unroll
        for (int m = 0; m < 4; ++m)
            af[m] = *(const bf16x8*)&Asl[(wr * 64 + m * 16 + lr) * 32 + lg * 8];
#pragma unroll
        for (int n = 0; n < 4; ++n)
            bfr[n] = *(const bf16x8*)&Bsl[(wc * 64 + n * 16 + lr) * 32 + lg * 8];
#pragma unroll
        for (int m = 0; m < 4; ++m)
#pragma unroll
            for (int n = 0; n < 4; ++n)
                acc[m][n] = __builtin_amdgcn_mfma_f32_16x16x32_bf16(af[m], bfr[n], acc[m][n], 0, 0, 0);
    }
#pragma unroll
    for (int m = 0; m < 4; ++m)
#pragma unroll
        for (int n = 0; n < 4; ++n) {
#pragma unroll
            for (int i = 0; i < 4; ++i) {
                int r  = row0 + wr * 64 + m * 16 + lg * 4 + i;
                int cc = col0 + wc * 64 + n * 16 + lr;
                size_t off = (size_t)r * N + cc;
                float v = acc[m][n][i];
                if (mode == 2) {
                    Cb[off] = f2bu(v);
                } else {
                    if (mode == 1) v += resid[off];
                    Cf[off] = v;
                }
            }
        }
}

// ---------------------------------------------------------------------------
// feat_mfma: out[m,r] = bf16( sqrt(2/R)*cos( dot(X[m,:64], omega[r,:64]) + b[r] ) )
// X bf16 [M2][64], omega bf16 [256][64]. 64-row tile, N=256, K=64 (2 k-steps).
// LDS staged split-K: [ks][row][32] so MFMA reads match the m97 pattern.
// ---------------------------------------------------------------------------
__launch_bounds__(256)
__global__ void feat_mfma(const unsigned short* __restrict__ X,
                          const unsigned short* __restrict__ om,
                          const float* __restrict__ bvec,
                          unsigned short* __restrict__ out) {
    __shared__ unsigned short Xs[2 * 64 * 32];    // 8 KB
    __shared__ unsigned short Os[2 * 256 * 32];   // 32 KB
    __shared__ unsigned short Rs[64][264];        // 33 KB repack
    const int t = threadIdx.x;
    const int lane = t & 63, w = t >> 6;
    const int lg = lane >> 4, lr = lane & 15;
    const int m0 = blockIdx.x * 64;

    // stage X: 512 chunks of 8 u16. LDS id = t*8 linear; decode (ks,row,sub).
#pragma unroll
    for (int i = 0; i < 2; ++i) {
        int cch = i * 256 + t;
        int ks = cch >> 8, row = (cch >> 2) & 63, sub = cch & 3;
        gload16(&X[(size_t)(m0 + row) * 64 + ks * 32 + sub * 8], &Xs[cch * 8]);
    }
    // stage omega: 2048 chunks of 8 u16.
#pragma unroll
    for (int i = 0; i < 8; ++i) {
        int cch = i * 256 + t;
        int ks = cch >> 10, r = (cch >> 2) & 255, sub = cch & 3;
        gload16(&om[(size_t)r * 64 + ks * 32 + sub * 8], &Os[cch * 8]);
    }
    __syncthreads();

    f32x4 acc[4][4] = {};
#pragma unroll
    for (int ks = 0; ks < 2; ++ks) {
        bf16x8 af[4], bfr[4];
#pragma unroll
        for (int m = 0; m < 4; ++m)
            af[m] = *(const bf16x8*)&Xs[ks * 2048 + (m * 16 + lr) * 32 + lg * 8];
#pragma unroll
        for (int n = 0; n < 4; ++n)
            bfr[n] = *(const bf16x8*)&Os[ks * 8192 + (w * 64 + n * 16 + lr) * 32 + lg * 8];
#pragma unroll
        for (int m = 0; m < 4; ++m)
#pragma unroll
            for (int n = 0; n < 4; ++n)
                acc[m][n] = __builtin_amdgcn_mfma_f32_16x16x32_bf16(af[m], bfr[n], acc[m][n], 0, 0, 0);
    }

    const float scale = 0.08838834764831845f;  // sqrt(2/256)
#pragma unroll
    for (int n = 0; n < 4; ++n) {
        const int col = w * 64 + n * 16 + lr;
        const float bb = bvec[col];
#pragma unroll
        for (int m = 0; m < 4; ++m)
#pragma unroll
            for (int ii = 0; ii < 4; ++ii)
                Rs[m * 16 + lg * 4 + ii][col] = f2bu(scale * __cosf(acc[m][n][ii] + bb));
    }
    __syncthreads();
#pragma unroll
    for (int i = 0; i < 8; ++i) {
        int cch = i * 256 + t;
        int row = cch >> 5, colc = (cch & 31) * 8;
        u16x8 vv = *(const u16x8*)&Rs[row][colc];
        *(u16x8*)&out[(size_t)(m0 + row) * 256 + colc] = vv;
    }
}

// ---------------------------------------------------------------------------
// passA (MFMA): KV[r][d] = sum_l kp[l][r]*vb[l][d] (bf16 out), ksum[r].
// ---------------------------------------------------------------------------
__launch_bounds__(256)
__global__ void passA_mfma(const unsigned short* __restrict__ kp, const unsigned short* __restrict__ vb,
                           unsigned short* __restrict__ kv, float* __restrict__ ksum) {
    __shared__ __align__(16) unsigned short KPt[256][72];  // [r][l]
    __shared__ __align__(16) unsigned short Vt[64][72];    // [d][l]
    const int c = blockIdx.x, h = blockIdx.y, bz = blockIdx.z;
    const int t = threadIdx.x;
    const int lane = t & 63, w = t >> 6;
    const int lg = lane >> 4, lr = lane & 15;
    const int l0 = c * C_;
    const int bh = bz * H_ + h;

    {   // stage KP^T
        const int l4 = (t & 15) * 4, rs = (t >> 4) * 16;
        u16x8 row[4][2];
#pragma unroll
        for (int i = 0; i < 4; ++i) {
            const unsigned short* src = &kp[((size_t)(bz * L_ + l0 + l4 + i) * H_ + h) * R_ + rs];
            row[i][0] = *(const u16x8*)src;
            row[i][1] = *(const u16x8*)(src + 8);
        }
#pragma unroll
        for (int q = 0; q < 16; ++q) {
            u16x4 pk = { row[0][q >> 3][q & 7], row[1][q >> 3][q & 7],
                         row[2][q >> 3][q & 7], row[3][q >> 3][q & 7] };
            *(u16x4*)&KPt[rs + q][l4] = pk;
        }
    }
    {   // stage V^T (bf16 pass-through)
        const int d4 = (t & 15) * 4, ls = (t >> 4) * 4;
        u16x4 x[4];
#pragma unroll
        for (int i = 0; i < 4; ++i)
            x[i] = *(const u16x4*)&vb[(size_t)(bz * L_ + l0 + ls + i) * DM_ + h * 64 + d4];
#pragma unroll
        for (int q = 0; q < 4; ++q) {
            u16x4 pk = { x[0][q], x[1][q], x[2][q], x[3][q] };
            *(u16x4*)&Vt[d4 + q][ls] = pk;
        }
    }
    __syncthreads();

    f32x4 acc[4][4] = {};
#pragma unroll
    for (int ks = 0; ks < 2; ++ks) {
        bf16x8 af[4], bfr[4];
#pragma unroll
        for (int m = 0; m < 4; ++m)
            af[m] = *(const bf16x8*)&Vt[16 * m + lr][ks * 32 + lg * 8];
#pragma unroll
        for (int n = 0; n < 4; ++n)
            bfr[n] = *(const bf16x8*)&KPt[64 * w + 16 * n + lr][ks * 32 + lg * 8];
#pragma unroll
        for (int m = 0; m < 4; ++m)
#pragma unroll
            for (int n = 0; n < 4; ++n)
                acc[m][n] = __builtin_amdgcn_mfma_f32_16x16x32_bf16(af[m], bfr[n], acc[m][n], 0, 0, 0);
    }
    size_t kvbase = ((size_t)(bh * NC_ + c)) * R_ * 64;
#pragma unroll
    for (int m = 0; m < 4; ++m)
#pragma unroll
        for (int n = 0; n < 4; ++n) {
            int r = 64 * w + 16 * n + lr;
            int d = 16 * m + lg * 4;
            u16x4 pk = { f2bu(acc[m][n][0]), f2bu(acc[m][n][1]),
                         f2bu(acc[m][n][2]), f2bu(acc[m][n][3]) };
            *(u16x4*)&kv[kvbase + (size_t)r * 64 + d] = pk;
        }
    {
        float s = 0.f;
#pragma unroll
        for (int j = 0; j < 8; ++j) {
            u16x8 vv = *(const u16x8*)&KPt[t][j * 8];
#pragma unroll
            for (int q = 0; q < 8; ++q) s += bu2f(vv[q]);
        }
        ksum[((size_t)(bh * NC_ + c)) * R_ + t] = s;
    }
}

// ---------------------------------------------------------------------------
// passB: exclusive prefix over chunks; one (r,d) chain per thread.
// ---------------------------------------------------------------------------
__launch_bounds__(256)
__global__ void passB_chain(unsigned short* __restrict__ kv, float* __restrict__ ksum) {
    const int bx = blockIdx.x, h = blockIdx.y, bz = blockIdx.z;
    const int t = threadIdx.x;
    const int bh = bz * H_ + h;
    const int r = bx * 4 + (t >> 6);
    const int d = t & 63;
    size_t base = ((size_t)bh * NC_ * R_ + r) * 64 + d;
    const size_t cstride = (size_t)R_ * 64;
    float run = 0.f;
    for (int c = 0; c < NC_; ++c) {
        size_t idx = base + (size_t)c * cstride;
        float tmp = bu2f(kv[idx]);
        kv[idx] = f2bu(run);
        run += tmp;
    }
    if (bx == 0) {
        float rz = 0.f;
        for (int c = 0; c < NC_; ++c) {
            size_t idx = ((size_t)bh * NC_ + c) * R_ + t;
            float tmp = ksum[idx];
            ksum[idx] = rz;
            rz += tmp;
        }
    }
}

// ---------------------------------------------------------------------------
// passC (MFMA): A = mask(QP@KP^T); [num|den] = A@[V^T|1] + QP@[Spref^T|z];
// out bf16 = num / (max(den,1e-6)+1e-6).
// ---------------------------------------------------------------------------
__launch_bounds__(256)
__global__ void passC_mfma(const unsigned short* __restrict__ qp, const unsigned short* __restrict__ kp,
                           const unsigned short* __restrict__ vb, const unsigned short* __restrict__ kvpref,
                           const float* __restrict__ zpref, unsigned short* __restrict__ attnb) {
    __shared__ __align__(16) unsigned short SprefT[80][264];  // [d][r], row64=zpref
    __shared__ __align__(16) unsigned short Vt[80][72];       // [d][l], row64=ones
    __shared__ __align__(16) unsigned short As[64][72];       // masked scores

    const int c = blockIdx.x, h = blockIdx.y, bz = blockIdx.z;
    const int t = threadIdx.x;
    const int lane = t & 63, w = t >> 6;
    const int lg = lane >> 4, lr = lane & 15;
    const int l0 = c * C_;
    const int bh = bz * H_ + h;

    {   // stage Spref^T from kv [r][d]
        const int r4 = (t & 63) * 4, ds = (t >> 6) * 16;
        u16x8 row[4][2];
#pragma unroll
        for (int i = 0; i < 4; ++i) {
            const unsigned short* src = &kvpref[(((size_t)(bh * NC_ + c)) * R_ + r4 + i) * 64 + ds];
            row[i][0] = *(const u16x8*)src;
            row[i][1] = *(const u16x8*)(src + 8);
        }
#pragma unroll
        for (int q = 0; q < 16; ++q) {
            u16x4 pk = { row[0][q >> 3][q & 7], row[1][q >> 3][q & 7],
                         row[2][q >> 3][q & 7], row[3][q >> 3][q & 7] };
            *(u16x4*)&SprefT[ds + q][r4] = pk;
        }
    }
    if (t < 32) {
        f4 z0 = *(const f4*)&zpref[((size_t)(bh * NC_ + c)) * R_ + t * 8];
        f4 z1 = *(const f4*)&zpref[((size_t)(bh * NC_ + c)) * R_ + t * 8 + 4];
        u16x8 pk = { f2bu(z0[0]), f2bu(z0[1]), f2bu(z0[2]), f2bu(z0[3]),
                     f2bu(z1[0]), f2bu(z1[1]), f2bu(z1[2]), f2bu(z1[3]) };
        *(u16x8*)&SprefT[64][t * 8] = pk;
    }
    for (int i = t; i < 15 * 264; i += 256) SprefT[65 + i / 264][i % 264] = 0;

    {   // stage V^T (bf16 pass-through)
        const int d4 = (t & 15) * 4, ls = (t >> 4) * 4;
        u16x4 x[4];
#pragma unroll
        for (int i = 0; i < 4; ++i)
            x[i] = *(const u16x4*)&vb[(size_t)(bz * L_ + l0 + ls + i) * DM_ + h * 64 + d4];
#pragma unroll
        for (int q = 0; q < 4; ++q) {
            u16x4 pk = { x[0][q], x[1][q], x[2][q], x[3][q] };
            *(u16x4*)&Vt[d4 + q][ls] = pk;
        }
    }
    if (t < 16) {
        u16x4 ones = { 0x3F80, 0x3F80, 0x3F80, 0x3F80 };
        *(u16x4*)&Vt[64][t * 4] = ones;
    }
    for (int i = t; i < 15 * 72; i += 256) Vt[65 + i / 72][i % 72] = 0;

    // scores
    const size_t qrow = ((size_t)(bz * L_ + l0 + 16 * w + lr) * H_ + h) * R_;
    f32x4 sacc[4] = {};
#pragma unroll
    for (int ks = 0; ks < 8; ++ks) {
        bf16x8 aq = *(const bf16x8*)&qp[qrow + ks * 32 + lg * 8];
#pragma unroll
        for (int n = 0; n < 4; ++n) {
            bf16x8 bk = *(const bf16x8*)&kp[((size_t)(bz * L_ + l0 + 16 * n + lr) * H_ + h) * R_ + ks * 32 + lg * 8];
            sacc[n] = __builtin_amdgcn_mfma_f32_16x16x32_bf16(aq, bk, sacc[n], 0, 0, 0);
        }
    }
#pragma unroll
    for (int n = 0; n < 4; ++n)
#pragma unroll
        for (int ii = 0; ii < 4; ++ii) {
            int i_loc = 16 * w + lg * 4 + ii;
            int j_loc = 16 * n + lr;
            As[i_loc][j_loc] = (j_loc <= i_loc) ? f2bu(sacc[n][ii]) : (unsigned short)0;
        }
    __syncthreads();

    f32x4 oacc[5] = {};
#pragma unroll
    for (int ks = 0; ks < 2; ++ks) {
        bf16x8 aa = *(const bf16x8*)&As[16 * w + lr][ks * 32 + lg * 8];
#pragma unroll
        for (int n = 0; n < 5; ++n) {
            bf16x8 bv = *(const bf16x8*)&Vt[16 * n + lr][ks * 32 + lg * 8];
            oacc[n] = __builtin_amdgcn_mfma_f32_16x16x32_bf16(aa, bv, oacc[n], 0, 0, 0);
        }
    }
#pragma unroll
    for (int ks = 0; ks < 8; ++ks) {
        bf16x8 aq = *(const bf16x8*)&qp[qrow + ks * 32 + lg * 8];
#pragma unroll
        for (int n = 0; n < 5; ++n) {
            bf16x8 bs = *(const bf16x8*)&SprefT[16 * n + lr][ks * 32 + lg * 8];
            oacc[n] = __builtin_amdgcn_mfma_f32_16x16x32_bf16(aq, bs, oacc[n], 0, 0, 0);
        }
    }
#pragma unroll
    for (int ii = 0; ii < 4; ++ii) {
        float den = __shfl(oacc[4][ii], lane & 48, 64);
        float inv = 1.f / (fmaxf(den, 1e-6f) + 1e-6f);
#pragma unroll
        for (int n = 0; n < 4; ++n)
            attnb[(size_t)(bz * L_ + l0 + 16 * w + lg * 4 + ii) * DM_ + h * 64 + 16 * n + lr] =
                f2bu(oacc[n][ii] * inv);
    }
}

// ---------------------------------------------------------------------------
// In-place row LayerNorm over last dim (1024), eps=1e-5.
// ---------------------------------------------------------------------------
__launch_bounds__(256)
__global__ void ln_kernel(float* __restrict__ io, const float* __restrict__ gamma,
                          const float* __restrict__ beta) {
    __shared__ float wsum[4], wsum2[4];
    const int row = blockIdx.x;
    const int t = threadIdx.x;
    f4 x = *(const f4*)&io[(size_t)row * DM_ + t * 4];
    float s  = x[0] + x[1] + x[2] + x[3];
    float s2 = x[0]*x[0] + x[1]*x[1] + x[2]*x[2] + x[3]*x[3];
#pragma unroll
    for (int o = 32; o > 0; o >>= 1) {
        s  += __shfl_down(s, o);
        s2 += __shfl_down(s2, o);
    }
    if ((t & 63) == 0) { wsum[t >> 6] = s; wsum2[t >> 6] = s2; }
    __syncthreads();
    s  = wsum[0]  + wsum[1]  + wsum[2]  + wsum[3];
    s2 = wsum2[0] + wsum2[1] + wsum2[2] + wsum2[3];
    const float m = s * (1.f / DM_);
    const float var = s2 * (1.f / DM_) - m * m;
    const float rstd = rsqrtf(var + 1e-5f);
    f4 g  = *(const f4*)&gamma[t * 4];
    f4 bb = *(const f4*)&beta[t * 4];
    f4 o = (x - m) * rstd * g + bb;
    *(f4*)&io[(size_t)row * DM_ + t * 4] = o;
}

// ---------------------------------------------------------------------------
// Workspace (226 MB):
//   [  0, 64) qp bf16
//   [ 64,128) kp bf16        | step1: aq [64,80) + wq_bf [80,82) | step8: wo_bf [64,66)
//   [128,192) kv bf16        | ak/av [128,144) + wk/wv [144,146) + omega_bf [146,147)
//   [192,208) vb bf16        | step1-2: qx bf16
//   [208,224) attnb bf16     | step3: kx bf16
//   [224,226) ksum f32
// ---------------------------------------------------------------------------
extern "C" void kernel_launch(void* const* d_in, const int* in_sizes, int n_in,
                              void* d_out, int out_size, void* d_ws, size_t ws_size,
                              hipStream_t stream) {
    const float* pre_q = (const float*)d_in[0];
    const float* pre_k = (const float*)d_in[1];
    const float* pre_v = (const float*)d_in[2];
    const float* wq    = (const float*)d_in[3];
    const float* wk    = (const float*)d_in[4];
    const float* wv    = (const float*)d_in[5];
    const float* wo    = (const float*)d_in[6];
    const float* gamma = (const float*)d_in[7];
    const float* beta  = (const float*)d_in[8];
    const float* omega = (const float*)d_in[9];
    const float* bvec  = (const float*)d_in[10];

    const size_t NEED = 226ull << 20;
    if (ws_size < NEED) return;

    char* w = (char*)d_ws;
    unsigned short* qp    = (unsigned short*)(w);
    unsigned short* kp    = (unsigned short*)(w + (64ull << 20));
    unsigned short* kvb   = (unsigned short*)(w + (128ull << 20));
    unsigned short* vb    = (unsigned short*)(w + (192ull << 20));
    unsigned short* attnb = (unsigned short*)(w + (208ull << 20));
    float*          ksum  = (float*)(w + (224ull << 20));
    // transient staging
    unsigned short* aq    = (unsigned short*)(w + (64ull << 20));    // in kp slot
    unsigned short* wq_bf = (unsigned short*)(w + (80ull << 20));
    unsigned short* qx    = vb;                                      // in vb slot
    unsigned short* akv   = (unsigned short*)(w + (128ull << 20));   // in kv slot (ak, av)
    unsigned short* wkv   = (unsigned short*)(w + (144ull << 20));   // (wk, wv)
    unsigned short* om_bf = (unsigned short*)(w + (146ull << 20));
    unsigned short* kx    = attnb;                                   // in attnb slot
    unsigned short* wo_bf = (unsigned short*)(w + (64ull << 20));    // kp dead after passC
    float*          outb  = (float*)d_out;

    const int n4_big = M_ * DM_ / 4;
    const int n4_w   = DM_ * DM_ / 4;
    const int n4_om  = R_ * D_ / 4;
    dim3 gg(DM_ / 128, M_ / 128);

    cvt_bf16<<<(n4_om + 255) / 256, 256, 0, stream>>>(omega, om_bf, n4_om);

    // Q -> qx (bf16) -> qp
    cvt_bf16<<<(n4_big + 255) / 256, 256, 0, stream>>>(pre_q, aq, n4_big);
    cvt_bf16<<<(n4_w + 255) / 256, 256, 0, stream>>>(wq, wq_bf, n4_w);
    gemm_mfma<<<gg, 256, 0, stream>>>(aq, wq_bf, nullptr, nullptr, qx, M_, DM_, DM_, 2);
    feat_mfma<<<M2_ / 64, 256, 0, stream>>>(qx, om_bf, bvec, qp);

    // K -> kx (bf16) -> kp
    cvt_bf16<<<(n4_big + 255) / 256, 256, 0, stream>>>(pre_k, akv, n4_big);
    cvt_bf16<<<(n4_w + 255) / 256, 256, 0, stream>>>(wk, wkv, n4_w);
    gemm_mfma<<<gg, 256, 0, stream>>>(akv, wkv, nullptr, nullptr, kx, M_, DM_, DM_, 2);
    feat_mfma<<<M2_ / 64, 256, 0, stream>>>(kx, om_bf, bvec, kp);

    // V -> vb (bf16)
    cvt_bf16<<<(n4_big + 255) / 256, 256, 0, stream>>>(pre_v, akv, n4_big);
    cvt_bf16<<<(n4_w + 255) / 256, 256, 0, stream>>>(wv, wkv, n4_w);
    gemm_mfma<<<gg, 256, 0, stream>>>(akv, wkv, nullptr, nullptr, vb, M_, DM_, DM_, 2);

    passA_mfma<<<dim3(NC_, H_, B_), 256, 0, stream>>>(kp, vb, kvb, ksum);
    passB_chain<<<dim3(64, H_, B_), 256, 0, stream>>>(kvb, ksum);
    passC_mfma<<<dim3(NC_, H_, B_), 256, 0, stream>>>(qp, kp, vb, kvb, ksum, attnb);

    // out-proj + residual + LN
    cvt_bf16<<<(n4_w + 255) / 256, 256, 0, stream>>>(wo, wo_bf, n4_w);
    gemm_mfma<<<gg, 256, 0, stream>>>(attnb, wo_bf, pre_q, outb, nullptr, M_, DM_, DM_, 1);
    ln_kernel<<<M_, 256, 0, stream>>>(outb, gamma, beta);
}